// Round 9
// baseline (373.008 us; speedup 1.0000x reference)
//
#include <hip/hip_runtime.h>
#include <hip/hip_cooperative_groups.h>
#include <cstdint>

#define BATCH 4
#define TQ 256
#define TK 256
#define DIM 256
#define HD 256

typedef _Float16 f16x8 __attribute__((ext_vector_type(8)));
typedef float f32x4 __attribute__((ext_vector_type(4)));

union U4H8 { uint4 u; f16x8 v; };

__device__ __forceinline__ unsigned short f2h(float f) {
    _Float16 h = (_Float16)f;
    unsigned short u;
    __builtin_memcpy(&u, &h, 2);
    return u;
}

__device__ __forceinline__ float h2f(unsigned short u) {
    _Float16 h;
    __builtin_memcpy(&h, &u, 2);
    return (float)h;
}

__device__ __forceinline__ uint32_t pk2h(float a, float b) {
    auto r = __builtin_amdgcn_cvt_pkrtz(a, b);
    uint32_t w;
    __builtin_memcpy(&w, &r, 4);
    return w;
}

// ONE cooperative kernel: 256 blocks x 512 threads (1 block/CU co-resident).
// Phase 1: pack (X hi/lo split, W1T hi/lo transpose, W2T f16 transpose)
// Phase 2: qkh = [queries@W1hi + b1 ; keys@W1lo] via 3-term f16 MFMA (fp32-exact)
// Phase 3: per block, 4 (b,q) units: MFMA scores (B register-resident),
//          LDS-atomic epilogue, softmax, split-k PV. b3 dropped (softmax-inv).
__global__ __launch_bounds__(512, 2) void fused_all(
    const float* __restrict__ queries, const float* __restrict__ keys,
    const int* __restrict__ qlens, const int* __restrict__ klens,
    const float* __restrict__ W1, const float* __restrict__ b1,
    const float* __restrict__ W2, const float* __restrict__ b2,
    const float* __restrict__ W3, float* __restrict__ out,
    float* __restrict__ qkh,
    unsigned short* __restrict__ Xh, unsigned short* __restrict__ Xl,
    unsigned short* __restrict__ W1Th, unsigned short* __restrict__ W1Tl,
    unsigned short* __restrict__ W2T) {
    cooperative_groups::grid_group grid = cooperative_groups::this_grid();
    const int bid = blockIdx.x;
    const int t = threadIdx.x;
    const int wv = t >> 6, lane = t & 63;
    const int col = lane & 15, quad = lane >> 4;

    // ================= phase 1: pack =================
    {
        int g = bid * 512 + t;          // 0..131071
        // X = [queries; keys] hi/lo split, one float4 per thread
        const float4* qf = (const float4*)queries;
        const float4* kf = (const float4*)keys;
        float4 v = (g < 65536) ? qf[g] : kf[g - 65536];
        uint32_t h0 = pk2h(v.x, v.y), h1 = pk2h(v.z, v.w);
        float f0 = h2f((unsigned short)h0), f1 = h2f((unsigned short)(h0 >> 16));
        float f2 = h2f((unsigned short)h1), f3 = h2f((unsigned short)(h1 >> 16));
        uint32_t l0 = pk2h(v.x - f0, v.y - f1), l1 = pk2h(v.z - f2, v.w - f3);
        ((uint2*)Xh)[g] = make_uint2(h0, h1);
        ((uint2*)Xl)[g] = make_uint2(l0, l1);
        // W1T hi/lo: W1Th/l[n][k] = split(W1[k][n]), one element per thread
        int n1 = g >> 9, k1 = g & 511;
        float w = W1[k1 * HD + n1];
        unsigned short hh = f2h(w);
        W1Th[n1 * 512 + k1] = hh;
        W1Tl[n1 * 512 + k1] = f2h(w - h2f(hh));
        // W2T[n][c] = f16(W2[c][n]), first half of threads
        if (g < 65536) {
            int n2 = g >> 8, c2 = g & 255;
            W2T[n2 * HD + c2] = f2h(W2[c2 * HD + n2]);
        }
    }
    grid.sync();

    // ================= phase 2: qkh via MFMA =================
    {
        int mblk = bid >> 3;                 // 0..31 (64 m-rows each)
        int n0 = (bid & 7) * 32;             // 32-n slice
        int mbase = mblk * 64 + (wv & 3) * 16;
        int arow = mbase + col;
        bool isQ = mblk < 16;
        int koff = isQ ? 256 : 0;            // queries use W1 rows 256..511
        int n = n0 + (wv >> 2) * 16 + col;
        const uint4* axh = (const uint4*)(Xh + arow * DIM) + quad;
        const uint4* axl = (const uint4*)(Xl + arow * DIM) + quad;
        const uint4* pbh = (const uint4*)(W1Th + n * 512 + koff) + quad;
        const uint4* pbl = (const uint4*)(W1Tl + n * 512 + koff) + quad;
        f32x4 acc = {};
#pragma unroll
        for (int s = 0; s < 8; ++s) {
            U4H8 ah, al, bh, bl;
            ah.u = axh[s * 4];
            al.u = axl[s * 4];
            bh.u = pbh[s * 4];
            bl.u = pbl[s * 4];
            acc = __builtin_amdgcn_mfma_f32_16x16x32_f16(ah.v, bh.v, acc, 0, 0, 0);
            acc = __builtin_amdgcn_mfma_f32_16x16x32_f16(al.v, bh.v, acc, 0, 0, 0);
            acc = __builtin_amdgcn_mfma_f32_16x16x32_f16(ah.v, bl.v, acc, 0, 0, 0);
        }
        float b1v = isQ ? b1[n] : 0.f;
#pragma unroll
        for (int r = 0; r < 4; ++r)
            qkh[(mbase + quad * 4 + r) * HD + n] = acc[r] + b1v;
    }
    grid.sync();

    // ================= phase 3: scores + softmax + PV =================
    __shared__ uint4 Afrag[8][4][64];     // 32 KB
    __shared__ float srow[TK];
    __shared__ float ep[64][17];          // per-chunk n-reduction scratch
    __shared__ float redm[8], reds[8];
    __shared__ float outp[2][256];

    const float* qh = qkh;                       // rows 0..1023
    const float* kh = qkh + 1024 * HD;           // rows 1024..2047

    // B register-resident: wave wv owns n in [wv*32, wv*32+32): 2x8 uint4 = 64 VGPR
    uint4 bfr[2][8];
    float b2v[2], w3v[2];
#pragma unroll
    for (int nt = 0; nt < 2; ++nt) {
        int n = wv * 32 + nt * 16 + col;
        const uint4* w2r = (const uint4*)(W2T + n * HD) + quad;  // +quad = c-octet
#pragma unroll
        for (int s = 0; s < 8; ++s) bfr[nt][s] = w2r[s * 4];     // s*4 ONLY (R6 fix)
        b2v[nt] = b2[n];
        w3v[nt] = W3[n];
    }

    // staging role (R8-verified): wave stages m-tile (wv&3), k-steps (wv>>2)*4..+4
    const int mt_s = wv & 3, s0 = (wv >> 2) << 2;
    const int p = (mt_s << 4) | col;

    for (int u = 0; u < 4; ++u) {
        int b = u, q = bid;
        float* orow = out + (b * TQ + q) * DIM;
        int qlen = qlens[b], klen = klens[b];
        if (q >= qlen) {                    // uniform per block
            if (t < 256) orow[t] = 0.f;
            continue;
        }
        int nch = (klen + 63) >> 6;
        const float* qrow = qh + (b * TQ + q) * HD + quad * 8;   // b1 pre-folded
        const float* kbase = kh + (b * TK) * HD + quad * 8;

        for (int c = 0; c < nch; ++c) {
            if (c | u) __syncthreads();     // prior reads of Afrag/ep complete
            // zero ep
#pragma unroll
            for (int j = t; j < 64 * 17; j += 512) (&ep[0][0])[j] = 0.f;
            // stage chunk c (4 k-steps per thread)
            {
                const float* krow = kbase + (c * 64 + p) * HD;
                uint4* dst = &Afrag[s0][mt_s][lane];
#pragma unroll 2
                for (int s = 0; s < 4; ++s) {
                    int c0 = (s0 + s) * 32;
                    const float4 k0 = *(const float4*)(krow + c0);
                    const float4 k1 = *(const float4*)(krow + c0 + 4);
                    const float4 q0 = *(const float4*)(qrow + c0);
                    const float4 q1 = *(const float4*)(qrow + c0 + 4);
                    uint4 w;
                    w.x = pk2h(fmaxf(k0.x + q0.x, 0.f), fmaxf(k0.y + q0.y, 0.f));
                    w.y = pk2h(fmaxf(k0.z + q0.z, 0.f), fmaxf(k0.w + q0.w, 0.f));
                    w.z = pk2h(fmaxf(k1.x + q1.x, 0.f), fmaxf(k1.y + q1.y, 0.f));
                    w.w = pk2h(fmaxf(k1.z + q1.z, 0.f), fmaxf(k1.w + q1.w, 0.f));
                    dst[s * 256] = w;
                }
            }
            __syncthreads();                // A tile + ep-zero visible

            f32x4 acc[4][2] = {};
#pragma unroll
            for (int s = 0; s < 8; ++s) {
#pragma unroll
                for (int mt = 0; mt < 4; ++mt) {
                    U4H8 au;
                    au.u = Afrag[s][mt][lane];
#pragma unroll
                    for (int nt = 0; nt < 2; ++nt) {
                        U4H8 bu;
                        bu.u = bfr[nt][s];
                        acc[mt][nt] = __builtin_amdgcn_mfma_f32_16x16x32_f16(
                            au.v, bu.v, acc[mt][nt], 0, 0, 0);
                    }
                }
            }

            // epilogue: relu(+b2)*W3, 16 LDS atomics/lane into ep[k][col]
#pragma unroll
            for (int mt = 0; mt < 4; ++mt)
#pragma unroll
                for (int r = 0; r < 4; ++r) {
                    float pa = 0.f;
#pragma unroll
                    for (int nt = 0; nt < 2; ++nt)
                        pa = fmaf(fmaxf(acc[mt][nt][r] + b2v[nt], 0.f), w3v[nt], pa);
                    atomicAdd(&ep[mt * 16 + quad * 4 + r][col], pa);
                }
            __syncthreads();                // atomics done
            if (t < 64) {                   // fold 16 cols -> score
                float s = 0.f;
#pragma unroll
                for (int j = 0; j < 16; ++j) s += ep[t][j];
                srow[c * 64 + t] = s;
            }
        }
        __syncthreads();                    // srow complete

        // ---- masked softmax (waves 4..7 contribute -inf/0) ----
        float s = (t < klen) ? srow[t] : -3.4e38f;
        float m = s;
#pragma unroll
        for (int off = 1; off < 64; off <<= 1) m = fmaxf(m, __shfl_xor(m, off, 64));
        if (lane == 0) redm[wv] = m;
        __syncthreads();
        m = fmaxf(fmaxf(redm[0], redm[1]), fmaxf(redm[2], redm[3]));
        float e = (t < klen) ? __expf(s - m) : 0.f;
        float sum = e;
#pragma unroll
        for (int off = 1; off < 64; off <<= 1) sum += __shfl_xor(sum, off, 64);
        if (lane == 0) reds[wv] = sum;
        __syncthreads();
        float denom = reds[0] + reds[1] + reds[2] + reds[3];
        if (t < TK) srow[t] = e / denom;    // probs
        __syncthreads();

        // ---- PV split-k: half = t>>8 covers k in [half*128, ...) ----
        {
            int d = t & 255, half = t >> 8;
            int kstart = half * 128;
            int kend = min(klen, kstart + 128);
            float acc = 0.f;
            const float* kp = keys + b * TK * DIM + d;
#pragma unroll 8
            for (int k = kstart; k < kend; ++k) acc = fmaf(srow[k], kp[k * DIM], acc);
            outp[half][d] = acc;
        }
        __syncthreads();
        if (t < 256) orow[t] = outp[0][t] + outp[1][t];
    }
}

extern "C" void kernel_launch(void* const* d_in, const int* in_sizes, int n_in,
                              void* d_out, int out_size, void* d_ws, size_t ws_size,
                              hipStream_t stream) {
    (void)in_sizes; (void)n_in; (void)out_size; (void)ws_size;
    const float* queries = (const float*)d_in[0];
    const float* keys    = (const float*)d_in[1];
    const int*   qlens   = (const int*)d_in[2];
    const int*   klens   = (const int*)d_in[3];
    const float* W1      = (const float*)d_in[4];
    const float* b1      = (const float*)d_in[5];
    const float* W2      = (const float*)d_in[6];
    const float* b2      = (const float*)d_in[7];
    const float* W3      = (const float*)d_in[8];
    float* out = (float*)d_out;

    float* qkh = (float*)d_ws;                                   // 2 MB
    unsigned short* Xh   = (unsigned short*)(qkh + 2048 * HD);   // 1 MB
    unsigned short* Xl   = Xh + 2048 * DIM;                      // 1 MB
    unsigned short* W1Th = Xl + 2048 * DIM;                      // 256 KB
    unsigned short* W1Tl = W1Th + 256 * 512;                     // 256 KB
    unsigned short* W2T  = W1Tl + 256 * 512;                     // 128 KB

    void* args[] = {
        (void*)&queries, (void*)&keys, (void*)&qlens, (void*)&klens,
        (void*)&W1, (void*)&b1, (void*)&W2, (void*)&b2, (void*)&W3,
        (void*)&out, (void*)&qkh, (void*)&Xh, (void*)&Xl,
        (void*)&W1Th, (void*)&W1Tl, (void*)&W2T,
    };
    hipLaunchCooperativeKernel((const void*)fused_all, dim3(256), dim3(512),
                               args, 0, stream);
}